// Round 9
// baseline (767900.488 us; speedup 1.0000x reference)
//
#include <hip/hip_runtime.h>
#include <math.h>

#define T_STEPS 22550
#define NWG 32
#define NTHR 256

typedef unsigned long long ull;

// ---- u64 slot indices ----
#define SL_PRE  0                 // [512 elems][4]: pr, pz, pna, hn  (pre-activations)
#define SL_AM1  2048              // [32] per-WG c-logit max
#define SL_AM2  2080              // [2][32] per-WG f-logit max, parity banks
#define SL_END  2144

// ---- float offsets in ws ----
#define OF_SLOT  64
#define OF_AFTER (OF_SLOT + SL_END*2)
#define OF_BUFA  OF_AFTER                 // conv stage0 out [128][412]
#define OF_BUFB  (OF_BUFA + 128*412)      // conv stage1 out [128][2052]
#define OF_COND  (OF_BUFB + 128*2052)     // cond [T][128]

__global__ void k_init(float* ws){
  int i = blockIdx.x*blockDim.x + threadIdx.x;
  ull* sl = (ull*)(ws + OF_SLOT);
  if (i < SL_END) __hip_atomic_store(&sl[i], 0ULL, __ATOMIC_RELAXED, __HIP_MEMORY_SCOPE_AGENT);
}

// transposed conv (lhs_dilation=sc), padding e, then relu.
// mode 0: y[c][j]; mode 1: write cond[t=j-1][c] (crop [1:-1], transpose)
__global__ void k_upconv(const float* __restrict__ x, int instride, int inoff,
                         const float* __restrict__ w, const float* __restrict__ b,
                         float* __restrict__ y, int Cin, int Lin, int K, int sc, int e,
                         int Lout, int mode)
{
  int j = blockIdx.x*blockDim.x + threadIdx.x;
  int c = blockIdx.y;
  if (j >= Lout) return;
  float acc = b[c];
  int kstart = ((e - j) % sc + sc) % sc;
  for (int i = 0; i < Cin; ++i){
    const float* wci = w + (c*Cin + i)*K;
    const float* xi  = x + i*instride + inoff;
    for (int k = kstart; k < K; k += sc){
      int qd = j - e + k;
      if (qd >= 0){
        int qq = qd / sc;
        if (qq < Lin) acc += wci[k]*xi[qq];
      }
    }
  }
  acc = fmaxf(acc, 0.f);
  if (mode == 0) y[c*Lout + j] = acc;
  else { int t = j - 1; if (t >= 0 && t < T_STEPS) y[t*128 + c] = acc; }
}

__device__ __forceinline__ float sigm(float x){ return 1.f/(1.f + expf(-x)); }

__device__ __forceinline__ void pub64(ull* p, ull pk){
  (void)__hip_atomic_exchange(p, pk, __ATOMIC_RELAXED, __HIP_MEMORY_SCOPE_AGENT);
}
__device__ __forceinline__ ull ld64(ull* p){
  return __hip_atomic_load(p, __ATOMIC_RELAXED, __HIP_MEMORY_SCOPE_AGENT);
}
__device__ __forceinline__ ull spin_am(ull* p, unsigned tag){
  ull pk = ld64(p);
  while ((unsigned)(pk & 0xFFFFFFu) != tag) pk = ld64(p);
  return pk;
}
__device__ __forceinline__ ull pack_data(float v, unsigned tag){
  return ((ull)__float_as_uint(v) << 32) | (ull)tag;
}

__launch_bounds__(NTHR)
__global__ void k_wavernn(const float* __restrict__ Wx, const float* __restrict__ bx,
                          const float* __restrict__ Wh, const float* __restrict__ bh,
                          const float* __restrict__ O1w, const float* __restrict__ O1b,
                          const float* __restrict__ O2w, const float* __restrict__ O2b,
                          const float* __restrict__ O3w, const float* __restrict__ O3b,
                          const float* __restrict__ O4w, const float* __restrict__ O4b,
                          float* ws, float* __restrict__ out)
{
  __shared__ __align__(16) float h_s[512];      // h state (locally maintained, all elems)
  __shared__ __align__(16) float m_s[128];
  __shared__ __align__(16) float h1_s[256];
  __shared__ __align__(16) float o_s[512];
  __shared__ __align__(16) float pr_s[512], pz_s[512], pna_s[512], hn_s[512];
  __shared__ __align__(16) float w1r_s[512], w1z_s[512], w1n_s[512];
  __shared__ __align__(16) float w2r_s[512], w2z_s[512], w2n_s[512];
  __shared__ __align__(16) float o1b_s[512], o3b_s[512];
  __shared__ float hg_s[48], xgb_s[48];
  __shared__ float red_s[8], sc_s[8];           // [0]=f_val [2]=c_cat [3]=c_new
  __shared__ float wc0_s[48], bx_s[48], bh_s[48];

  const int tid = threadIdx.x, g = blockIdx.x;
  ull* sl = (ull*)(ws + OF_SLOT);
  const float* cond = ws + OF_COND;
  float* out_samp = out;
  float* out_log  = out + T_STEPS;

  // ---- static preloads ----
  if (tid < 48){
    int row = (tid>>4)*512 + g + 32*(tid&15);
    wc0_s[tid] = Wx[(size_t)row*131 + 0];
    bx_s[tid]  = bx[row];
    bh_s[tid]  = bh[row];
  }
  for (int e = tid; e < 512; e += NTHR){
    w1r_s[e] = Wx[(size_t)e*131 + 1];
    w1z_s[e] = Wx[(size_t)(512+e)*131 + 1];
    w1n_s[e] = Wx[(size_t)(1024+e)*131 + 1];
    w2r_s[e] = Wx[(size_t)e*131 + 2];
    w2z_s[e] = Wx[(size_t)(512+e)*131 + 2];
    w2n_s[e] = Wx[(size_t)(1024+e)*131 + 2];
    o1b_s[e] = O1b[e];
    o3b_s[e] = O3b[e];
  }
  // O2/O4: 8 rows/WG {g+32*m8}, 32 lanes/row, stride-32 cols (register weights)
  const int m8 = tid>>5, l32 = tid&31;
  const int row2 = g + 32*m8;
  float wO2r[16], wO4r[16];
  #pragma unroll
  for (int k=0;k<16;++k){
    wO2r[k] = O2w[(size_t)row2*512 + l32 + 32*k];
    wO4r[k] = O4w[(size_t)row2*512 + l32 + 32*k];
  }
  const float bO2 = O2b[row2], bO4 = O4b[row2];
  // head layer-1 group pattern: 16 groups x 16 lanes; group does 32 rows
  const int grp = tid>>4, c16 = tid&15;

  h_s[tid] = 0.f; h_s[tid+256] = 0.f;
  if (tid < 128) m_s[tid] = cond[tid];
  if (tid == 0){ sc_s[0] = 0.f; sc_s[2] = 0.f; sc_s[3] = 0.f; }
  __syncthreads();

  // xgb = Wx[:,3:]@m + bx    (48 rows x 4 lanes)
  #define COMPUTE_WX() do { \
    if (tid < 192){ \
      const int li_ = tid>>2, q_ = tid&3; \
      const int row_ = (li_>>4)*512 + g + 32*(li_&15); \
      const float* WxR = Wx + (size_t)row_*131 + 3; \
      float aX = 0.f; \
      _Pragma("unroll") \
      for (int kk=0; kk<32; ++kk){ \
        int f_ = q_*32 + ((kk + 8*q_) & 31); \
        aX += WxR[f_]*m_s[f_]; \
      } \
      aX += __shfl_xor(aX,1); aX += __shfl_xor(aX,2); \
      if (q_ == 0) xgb_s[li_] = aX + bx_s[li_]; \
    } } while(0)

  // hg = Wh@h + bh           (48 rows x 4 lanes, bank-swizzled LDS reads of h_s)
  #define COMPUTE_WH() do { \
    if (tid < 192){ \
      const int li_ = tid>>2, q_ = tid&3; \
      const int row_ = (li_>>4)*512 + g + 32*(li_&15); \
      const float4* W4 = (const float4*)(Wh + (size_t)row_*512); \
      const float4* H4 = (const float4*)h_s; \
      float aH = 0.f; \
      _Pragma("unroll") \
      for (int kk=0; kk<32; ++kk){ \
        int f_ = q_*32 + ((kk + 2*q_) & 31); \
        float4 w = W4[f_], v = H4[f_]; \
        aH += w.x*v.x + w.y*v.y + w.z*v.z + w.w*v.w; \
      } \
      aH += __shfl_xor(aH,1); aH += __shfl_xor(aH,2); \
      if (q_ == 0) hg_s[li_] = aH + bh_s[li_]; \
    } } while(0)

  // publish own 16 elems' pre-gates: pr, pz, pna, hn  (64 slots, tid<64)
  #define PUB_PREGATES(TAGP) do { \
    if (tid < 64){ \
      const int i_ = tid>>2, c_ = tid&3; \
      const int e_ = g + 32*i_; \
      const float c0_ = sc_s[3]; \
      float v_; \
      if (c_ == 0)      v_ = xgb_s[i_]    + c0_*wc0_s[i_]    + hg_s[i_]; \
      else if (c_ == 1) v_ = xgb_s[16+i_] + c0_*wc0_s[16+i_] + hg_s[16+i_]; \
      else if (c_ == 2) v_ = xgb_s[32+i_] + c0_*wc0_s[32+i_]; \
      else              v_ = hg_s[32+i_]; \
      pub64(&sl[SL_PRE + e_*4 + c_], pack_data(v_, (TAGP))); \
    } } while(0)

  // bootstrap: h=0 -> hg=bh; xgb from m0; c_val(0)=0 -> publish pregates tag 1
  COMPUTE_WX();
  if (tid < 48) hg_s[tid] = bh_s[tid];
  __syncthreads();
  PUB_PREGATES(1u);

  for (int t = 0; t < T_STEPS; ++t){
    const unsigned tag = (unsigned)(t + 1);

    // ---- (A) gather pre-gates (elems tid, tid+256; 8 independent loads, then fix-up) ----
    {
      ull pk[8];
      #pragma unroll
      for (int c=0;c<4;++c){
        pk[c]   = ld64(&sl[SL_PRE + tid*4 + c]);
        pk[4+c] = ld64(&sl[SL_PRE + (tid+256)*4 + c]);
      }
      bool all;
      do {
        all = true;
        #pragma unroll
        for (int i=0;i<8;++i){
          if ((unsigned)pk[i] != tag){
            int slot = (i<4) ? (tid*4 + i) : ((tid+256)*4 + (i-4));
            pk[i] = ld64(&sl[SL_PRE + slot]);
            if ((unsigned)pk[i] != tag) all = false;
          }
        }
      } while (!all);
      pr_s[tid]      = __uint_as_float((unsigned)(pk[0] >> 32));
      pz_s[tid]      = __uint_as_float((unsigned)(pk[1] >> 32));
      pna_s[tid]     = __uint_as_float((unsigned)(pk[2] >> 32));
      hn_s[tid]      = __uint_as_float((unsigned)(pk[3] >> 32));
      pr_s[tid+256]  = __uint_as_float((unsigned)(pk[4] >> 32));
      pz_s[tid+256]  = __uint_as_float((unsigned)(pk[5] >> 32));
      pna_s[tid+256] = __uint_as_float((unsigned)(pk[6] >> 32));
      hn_s[tid+256]  = __uint_as_float((unsigned)(pk[7] >> 32));
    }
    // ---- am2(t-1) gather -> f_val; g0 writes sample(t-1) ----
    if (t > 0 && tid < 32){
      ull pk = spin_am(&sl[SL_AM2 + ((t-1) & 1)*32 + tid], tag - 1);
      float bv = __uint_as_float((unsigned)(pk >> 32));
      int   bi = (int)((pk >> 24) & 0xFFu);
      #pragma unroll
      for (int off=16; off>=1; off>>=1){
        float ov = __shfl_xor(bv,off); int oi = __shfl_xor(bi,off);
        if (ov > bv || (ov == bv && oi < bi)){ bv = ov; bi = oi; }
      }
      if (tid == 0){
        sc_s[0] = (float)bi/127.5f - 1.f;   // f_val(t)
        if (g == 0) out_samp[t-1] = (sc_s[2]*256.f + (float)bi)/32767.5f - 1.f;
      }
    }
    if (tid < 128 && t + 1 < T_STEPS) m_s[tid] = cond[(size_t)(t+1)*128 + tid];
    __syncthreads();

    // ---- (B) h1 finish for lower 256 elems (local, all WGs identical) ----
    {
      const float f = sc_s[0];
      float r = sigm(pr_s[tid]  + f*w1r_s[tid]);
      float z = sigm(pz_s[tid]  + f*w1z_s[tid]);
      float n = tanhf(pna_s[tid] + f*w1n_s[tid] + r*hn_s[tid]);
      h1_s[tid] = (1.f - z)*n + z*h_s[tid];
    }
    __syncthreads();

    // ---- (C) full o1 = relu(O1w@h1 + b) local (O1w streamed from L2) ----
    for (int rr = 0; rr < 32; ++rr){
      int row = grp*32 + rr;
      const float4* W4 = (const float4*)(O1w + (size_t)row*256 + c16*16);
      const float4* H4 = (const float4*)(h1_s + c16*16);
      float acc = 0.f;
      #pragma unroll
      for (int k=0;k<4;++k){
        float4 w = W4[k], v = H4[k];
        acc += w.x*v.x + w.y*v.y + w.z*v.z + w.w*v.w;
      }
      acc += __shfl_xor(acc,1); acc += __shfl_xor(acc,2);
      acc += __shfl_xor(acc,4); acc += __shfl_xor(acc,8);
      if (c16 == 0) o_s[row] = fmaxf(acc + o1b_s[row], 0.f);
    }
    __syncthreads();

    // ---- (D) O2 own 8 rows -> am1 publish ----
    {
      float acc = 0.f;
      #pragma unroll
      for (int k=0;k<16;++k) acc += wO2r[k]*o_s[l32 + 32*k];
      acc += __shfl_xor(acc,1); acc += __shfl_xor(acc,2); acc += __shfl_xor(acc,4);
      acc += __shfl_xor(acc,8); acc += __shfl_xor(acc,16);
      if (l32 == 0){ float v = acc + bO2; out_log[(size_t)t*512 + row2] = v; red_s[m8] = v; }
    }
    __syncthreads();
    if (tid == 0){
      float bv = red_s[0]; int bi = g;          // rows ascend with m -> strict > = first max
      #pragma unroll
      for (int m=1;m<8;++m){ float v = red_s[m]; if (v > bv){ bv = v; bi = g + 32*m; } }
      pub64(&sl[SL_AM1 + g],
            ((ull)__float_as_uint(bv) << 32) | ((ull)(unsigned)bi << 24) | tag);
    }

    // ---- (E) am1 gather -> c ----
    if (tid < 32){
      ull pk = spin_am(&sl[SL_AM1 + tid], tag);
      float bv = __uint_as_float((unsigned)(pk >> 32));
      int   bi = (int)((pk >> 24) & 0xFFu);
      #pragma unroll
      for (int off=16; off>=1; off>>=1){
        float ov = __shfl_xor(bv,off); int oi = __shfl_xor(bi,off);
        if (ov > bv || (ov == bv && oi < bi)){ bv = ov; bi = oi; }
      }
      if (tid == 0){ sc_s[2] = (float)bi; sc_s[3] = (float)bi/127.5f - 1.f; }
    }
    __syncthreads();

    // ---- (F) h2 finish for ALL 512 elems (local, redundant, bit-identical) ----
    {
      const float f = sc_s[0], cn = sc_s[3];
      #pragma unroll
      for (int hh=0; hh<2; ++hh){
        int e = tid + 256*hh;
        float r = sigm(pr_s[e]  + f*w1r_s[e] + cn*w2r_s[e]);
        float z = sigm(pz_s[e]  + f*w1z_s[e] + cn*w2z_s[e]);
        float n = tanhf(pna_s[e] + f*w1n_s[e] + cn*w2n_s[e] + r*hn_s[e]);
        h_s[e] = (1.f - z)*n + z*h_s[e];
      }
    }
    __syncthreads();

    // ---- (G) full o3 local + O4 own rows -> am2 publish ----
    for (int rr = 0; rr < 32; ++rr){
      int row = grp*32 + rr;
      const float4* W4 = (const float4*)(O3w + (size_t)row*256 + c16*16);
      const float4* H4 = (const float4*)(h_s + 256 + c16*16);
      float acc = 0.f;
      #pragma unroll
      for (int k=0;k<4;++k){
        float4 w = W4[k], v = H4[k];
        acc += w.x*v.x + w.y*v.y + w.z*v.z + w.w*v.w;
      }
      acc += __shfl_xor(acc,1); acc += __shfl_xor(acc,2);
      acc += __shfl_xor(acc,4); acc += __shfl_xor(acc,8);
      if (c16 == 0) o_s[row] = fmaxf(acc + o3b_s[row], 0.f);
    }
    __syncthreads();
    {
      float acc = 0.f;
      #pragma unroll
      for (int k=0;k<16;++k) acc += wO4r[k]*o_s[l32 + 32*k];
      acc += __shfl_xor(acc,1); acc += __shfl_xor(acc,2); acc += __shfl_xor(acc,4);
      acc += __shfl_xor(acc,8); acc += __shfl_xor(acc,16);
      if (l32 == 0){ float v = acc + bO4; out_log[(size_t)t*512 + 256 + row2] = v; red_s[m8] = v; }
    }
    __syncthreads();
    if (tid == 0){
      float bv = red_s[0]; int bi = g;
      #pragma unroll
      for (int m=1;m<8;++m){ float v = red_s[m]; if (v > bv){ bv = v; bi = g + 32*m; } }
      pub64(&sl[SL_AM2 + (t & 1)*32 + g],
            ((ull)__float_as_uint(bv) << 32) | ((ull)(unsigned)bi << 24) | tag);
    }

    // ---- (H) next step's xgb/hg from local h2, publish pre-gates(t+1) ----
    COMPUTE_WX();
    COMPUTE_WH();
    __syncthreads();
    if (t + 1 < T_STEPS) PUB_PREGATES((unsigned)(t + 2));
  }

  // final sample: gather am2(T-1)
  if (g == 0 && tid < 32){
    ull pk = spin_am(&sl[SL_AM2 + ((T_STEPS-1) & 1)*32 + tid], (unsigned)T_STEPS);
    float bv = __uint_as_float((unsigned)(pk >> 32));
    int   bi = (int)((pk >> 24) & 0xFFu);
    #pragma unroll
    for (int off=16; off>=1; off>>=1){
      float ov = __shfl_xor(bv,off); int oi = __shfl_xor(bi,off);
      if (ov > bv || (ov == bv && oi < bi)){ bv = ov; bi = oi; }
    }
    if (tid == 0) out_samp[T_STEPS-1] = (sc_s[2]*256.f + (float)bi)/32767.5f - 1.f;
  }
}

extern "C" void kernel_launch(void* const* d_in, const int* in_sizes, int n_in,
                              void* d_out, int out_size, void* d_ws, size_t ws_size,
                              hipStream_t stream)
{
  const float* mels  = (const float*)d_in[0];
  const float* up_w0 = (const float*)d_in[1]; const float* up_b0 = (const float*)d_in[2];
  const float* up_w1 = (const float*)d_in[3]; const float* up_b1 = (const float*)d_in[4];
  const float* up_w2 = (const float*)d_in[5]; const float* up_b2 = (const float*)d_in[6];
  const float* Wx  = (const float*)d_in[7];  const float* bx  = (const float*)d_in[8];
  const float* Wh  = (const float*)d_in[9];  const float* bh  = (const float*)d_in[10];
  const float* O1w = (const float*)d_in[11]; const float* O1b = (const float*)d_in[12];
  const float* O2w = (const float*)d_in[13]; const float* O2b = (const float*)d_in[14];
  const float* O3w = (const float*)d_in[15]; const float* O3b = (const float*)d_in[16];
  const float* O4w = (const float*)d_in[17]; const float* O4b = (const float*)d_in[18];
  float* ws  = (float*)d_ws;
  float* out = (float*)d_out;

  k_init<<<(SL_END + 255)/256, 256, 0, stream>>>(ws);

  // upsample: 84 -> 412 -> 2052 -> 22552 (crop [1:-1] -> cond[22550][128])
  k_upconv<<<dim3((412  +127)/128, 128), 128, 0, stream>>>(mels,        86,   1, up_w0, up_b0,
            ws+OF_BUFA,  80,   84, 11,  5, 3,   412, 0);
  k_upconv<<<dim3((2052 +127)/128, 128), 128, 0, stream>>>(ws+OF_BUFA, 412,   0, up_w1, up_b1,
            ws+OF_BUFB, 128,  412, 11,  5, 3,  2052, 0);
  k_upconv<<<dim3((22552+127)/128, 128), 128, 0, stream>>>(ws+OF_BUFB, 2052,  0, up_w2, up_b2,
            ws+OF_COND, 128, 2052, 23, 11, 6, 22552, 1);

  k_wavernn<<<NWG, NTHR, 0, stream>>>(Wx, bx, Wh, bh, O1w, O1b, O2w, O2b,
                                      O3w, O3b, O4w, O4b, ws, out);
}

// Round 10
// 295855.518 us; speedup vs baseline: 2.5955x; 2.5955x over previous
//
#include <hip/hip_runtime.h>
#include <math.h>

#define T_STEPS 22550
#define NWG 32
#define NTHR 256

typedef unsigned long long ull;

// ---- u64 slot indices ----
#define SL_PRE  0                 // [512 elems][4]: pr, pz, pna, hn (pre-activations)
#define SL_O1   2048              // [32][16] o1 rows (owner-major)
#define SL_O3   2560              // [32][16] o3 rows
#define SL_AM1  3072              // [32] per-WG c-logit max
#define SL_AM2  3104              // [2][32] per-WG f-logit max, parity banks
#define SL_END  3168

// ---- float offsets in ws ----
#define OF_SLOT  64
#define OF_AFTER (OF_SLOT + SL_END*2)
#define OF_BUFA  OF_AFTER                 // conv stage0 out [128][412]
#define OF_BUFB  (OF_BUFA + 128*412)      // conv stage1 out [128][2052]
#define OF_COND  (OF_BUFB + 128*2052)     // cond [T][128]

__global__ void k_init(float* ws){
  int i = blockIdx.x*blockDim.x + threadIdx.x;
  ull* sl = (ull*)(ws + OF_SLOT);
  if (i < SL_END) __hip_atomic_store(&sl[i], 0ULL, __ATOMIC_RELAXED, __HIP_MEMORY_SCOPE_AGENT);
}

// transposed conv (lhs_dilation=sc), padding e, then relu.
// mode 0: y[c][j]; mode 1: write cond[t=j-1][c] (crop [1:-1], transpose)
__global__ void k_upconv(const float* __restrict__ x, int instride, int inoff,
                         const float* __restrict__ w, const float* __restrict__ b,
                         float* __restrict__ y, int Cin, int Lin, int K, int sc, int e,
                         int Lout, int mode)
{
  int j = blockIdx.x*blockDim.x + threadIdx.x;
  int c = blockIdx.y;
  if (j >= Lout) return;
  float acc = b[c];
  int kstart = ((e - j) % sc + sc) % sc;
  for (int i = 0; i < Cin; ++i){
    const float* wci = w + (c*Cin + i)*K;
    const float* xi  = x + i*instride + inoff;
    for (int k = kstart; k < K; k += sc){
      int qd = j - e + k;
      if (qd >= 0){
        int qq = qd / sc;
        if (qq < Lin) acc += wci[k]*xi[qq];
      }
    }
  }
  acc = fmaxf(acc, 0.f);
  if (mode == 0) y[c*Lout + j] = acc;
  else { int t = j - 1; if (t >= 0 && t < T_STEPS) y[t*128 + c] = acc; }
}

__device__ __forceinline__ float sigm(float x){ return 1.f/(1.f + expf(-x)); }

__device__ __forceinline__ void pub64(ull* p, ull pk){
  (void)__hip_atomic_exchange(p, pk, __ATOMIC_RELAXED, __HIP_MEMORY_SCOPE_AGENT);
}
__device__ __forceinline__ ull ld64(ull* p){
  return __hip_atomic_load(p, __ATOMIC_RELAXED, __HIP_MEMORY_SCOPE_AGENT);
}
__device__ __forceinline__ float spin_data(ull* p, unsigned tag){
  ull pk = ld64(p);
  while ((unsigned)pk != tag) pk = ld64(p);
  return __uint_as_float((unsigned)(pk >> 32));
}
__device__ __forceinline__ ull spin_am(ull* p, unsigned tag){
  ull pk = ld64(p);
  while ((unsigned)(pk & 0xFFFFFFu) != tag) pk = ld64(p);
  return pk;
}
__device__ __forceinline__ ull pack_data(float v, unsigned tag){
  return ((ull)__float_as_uint(v) << 32) | (ull)tag;
}

__launch_bounds__(NTHR)
__global__ void k_wavernn(const float* __restrict__ Wx, const float* __restrict__ bx,
                          const float* __restrict__ Wh, const float* __restrict__ bh,
                          const float* __restrict__ O1w, const float* __restrict__ O1b,
                          const float* __restrict__ O2w, const float* __restrict__ O2b,
                          const float* __restrict__ O3w, const float* __restrict__ O3b,
                          const float* __restrict__ O4w, const float* __restrict__ O4b,
                          float* ws, float* __restrict__ out)
{
  __shared__ __align__(16) float h_s[512];       // h state (locally maintained)
  __shared__ __align__(16) float m_s[128];       // cond[t+1] (for WX at end of step)
  __shared__ __align__(16) float h1_s[256];
  __shared__ __align__(16) float o_s[512];
  __shared__ __align__(16) float pr_s[512], pz_s[512], pna_s[512], hn_s[512];
  __shared__ __align__(16) float w1r_s[512], w1z_s[512], w1n_s[512];
  __shared__ __align__(16) float w2r_s[512], w2z_s[512], w2n_s[512];
  __shared__ float hg_s[48], xgb_s[48];
  __shared__ float red_s[8], sc_s[8];            // [0]=f_val [2]=c_cat [3]=c_new
  __shared__ float wc0_s[48], bx_s[48], bh_s[48];

  const int tid = threadIdx.x, g = blockIdx.x;
  ull* sl = (ull*)(ws + OF_SLOT);
  const float* cond = ws + OF_COND;
  float* out_samp = out;
  float* out_log  = out + T_STEPS;

  // ---- static preloads ----
  if (tid < 48){
    int row = (tid>>4)*512 + g + 32*(tid&15);
    wc0_s[tid] = Wx[(size_t)row*131 + 0];
    bx_s[tid]  = bx[row];
    bh_s[tid]  = bh[row];
  }
  for (int e = tid; e < 512; e += NTHR){
    w1r_s[e] = Wx[(size_t)e*131 + 1];
    w1z_s[e] = Wx[(size_t)(512+e)*131 + 1];
    w1n_s[e] = Wx[(size_t)(1024+e)*131 + 1];
    w2r_s[e] = Wx[(size_t)e*131 + 2];
    w2z_s[e] = Wx[(size_t)(512+e)*131 + 2];
    w2n_s[e] = Wx[(size_t)(1024+e)*131 + 2];
  }
  // O1/O3: 16 rows/WG {g+32*m16}, 16 lanes/row, 16 contiguous cols/lane (register weights)
  const int m16 = tid>>4, c16 = tid&15;
  const int rowO1 = g + 32*m16;
  float wO1r[16], wO3r[16];
  #pragma unroll
  for (int k=0;k<16;++k){
    wO1r[k] = O1w[(size_t)rowO1*256 + c16*16 + k];
    wO3r[k] = O3w[(size_t)rowO1*256 + c16*16 + k];
  }
  const float bO1r = O1b[rowO1], bO3r = O3b[rowO1];
  // O2/O4: 8 rows/WG {g+32*m8}, 32 lanes/row, stride-32 cols (register weights)
  const int m8 = tid>>5, l32 = tid&31;
  const int row2 = g + 32*m8;
  float wO2r[16], wO4r[16];
  #pragma unroll
  for (int k=0;k<16;++k){
    wO2r[k] = O2w[(size_t)row2*512 + l32 + 32*k];
    wO4r[k] = O4w[(size_t)row2*512 + l32 + 32*k];
  }
  const float bO2 = O2b[row2], bO4 = O4b[row2];

  h_s[tid] = 0.f; h_s[tid+256] = 0.f;
  if (tid < 128) m_s[tid] = cond[tid];             // m(0) for bootstrap WX
  if (tid == 0){ sc_s[0] = 0.f; sc_s[2] = 0.f; sc_s[3] = 0.f; }
  __syncthreads();

  // xgb = Wx[:,3:]@m + bx    (48 rows x 4 lanes)
  #define COMPUTE_WX() do { \
    if (tid < 192){ \
      const int li_ = tid>>2, q_ = tid&3; \
      const int row_ = (li_>>4)*512 + g + 32*(li_&15); \
      const float* WxR = Wx + (size_t)row_*131 + 3; \
      float aX = 0.f; \
      _Pragma("unroll") \
      for (int kk=0; kk<32; ++kk){ \
        int f_ = q_*32 + ((kk + 8*q_) & 31); \
        aX += WxR[f_]*m_s[f_]; \
      } \
      aX += __shfl_xor(aX,1); aX += __shfl_xor(aX,2); \
      if (q_ == 0) xgb_s[li_] = aX + bx_s[li_]; \
    } } while(0)

  // hg = Wh@h + bh           (48 rows x 4 lanes, bank-swizzled LDS reads of h_s)
  #define COMPUTE_WH() do { \
    if (tid < 192){ \
      const int li_ = tid>>2, q_ = tid&3; \
      const int row_ = (li_>>4)*512 + g + 32*(li_&15); \
      const float4* W4 = (const float4*)(Wh + (size_t)row_*512); \
      const float4* H4 = (const float4*)h_s; \
      float aH = 0.f; \
      _Pragma("unroll") \
      for (int kk=0; kk<32; ++kk){ \
        int f_ = q_*32 + ((kk + 2*q_) & 31); \
        float4 w = W4[f_], v = H4[f_]; \
        aH += w.x*v.x + w.y*v.y + w.z*v.z + w.w*v.w; \
      } \
      aH += __shfl_xor(aH,1); aH += __shfl_xor(aH,2); \
      if (q_ == 0) hg_s[li_] = aH + bh_s[li_]; \
    } } while(0)

  // publish own 16 elems' pre-gates: pr, pz, pna, hn  (64 slots, tid<64)
  #define PUB_PREGATES(TAGP) do { \
    if (tid < 64){ \
      const int i_ = tid>>2, c_ = tid&3; \
      const int e_ = g + 32*i_; \
      const float c0_ = sc_s[3]; \
      float v_; \
      if (c_ == 0)      v_ = xgb_s[i_]    + c0_*wc0_s[i_]    + hg_s[i_]; \
      else if (c_ == 1) v_ = xgb_s[16+i_] + c0_*wc0_s[16+i_] + hg_s[16+i_]; \
      else if (c_ == 2) v_ = xgb_s[32+i_] + c0_*wc0_s[32+i_]; \
      else              v_ = hg_s[32+i_]; \
      pub64(&sl[SL_PRE + e_*4 + c_], pack_data(v_, (TAGP))); \
    } } while(0)

  // bootstrap: h=0 -> hg=bh; xgb from m(0); c_val(0)=0 -> publish pregates tag 1
  COMPUTE_WX();
  if (tid < 48) hg_s[tid] = bh_s[tid];
  __syncthreads();
  PUB_PREGATES(1u);

  for (int t = 0; t < T_STEPS; ++t){
    const unsigned tag = (unsigned)(t + 1);

    // ---- (A) gather pre-gates(t); am2(t-1) -> f; sample(t-1); load m(t+1) ----
    {
      ull pk[8];
      #pragma unroll
      for (int c=0;c<4;++c){
        pk[c]   = ld64(&sl[SL_PRE + tid*4 + c]);
        pk[4+c] = ld64(&sl[SL_PRE + (tid+256)*4 + c]);
      }
      bool all;
      do {
        all = true;
        #pragma unroll
        for (int i=0;i<8;++i){
          if ((unsigned)pk[i] != tag){
            int slot = (i<4) ? (tid*4 + i) : ((tid+256)*4 + (i-4));
            pk[i] = ld64(&sl[SL_PRE + slot]);
            if ((unsigned)pk[i] != tag) all = false;
          }
        }
      } while (!all);
      pr_s[tid]      = __uint_as_float((unsigned)(pk[0] >> 32));
      pz_s[tid]      = __uint_as_float((unsigned)(pk[1] >> 32));
      pna_s[tid]     = __uint_as_float((unsigned)(pk[2] >> 32));
      hn_s[tid]      = __uint_as_float((unsigned)(pk[3] >> 32));
      pr_s[tid+256]  = __uint_as_float((unsigned)(pk[4] >> 32));
      pz_s[tid+256]  = __uint_as_float((unsigned)(pk[5] >> 32));
      pna_s[tid+256] = __uint_as_float((unsigned)(pk[6] >> 32));
      hn_s[tid+256]  = __uint_as_float((unsigned)(pk[7] >> 32));
    }
    if (t > 0 && tid < 32){
      ull pk = spin_am(&sl[SL_AM2 + ((t-1) & 1)*32 + tid], tag - 1);
      float bv = __uint_as_float((unsigned)(pk >> 32));
      int   bi = (int)((pk >> 24) & 0xFFu);
      #pragma unroll
      for (int off=16; off>=1; off>>=1){
        float ov = __shfl_xor(bv,off); int oi = __shfl_xor(bi,off);
        if (ov > bv || (ov == bv && oi < bi)){ bv = ov; bi = oi; }
      }
      if (tid == 0){
        sc_s[0] = (float)bi/127.5f - 1.f;   // f_val(t)
        if (g == 0) out_samp[t-1] = (sc_s[2]*256.f + (float)bi)/32767.5f - 1.f;
      }
    }
    if (tid < 128 && t + 1 < T_STEPS) m_s[tid] = cond[(size_t)(t+1)*128 + tid];
    __syncthreads();

    // ---- (B) h1 local for lower 256 elems (bit-identical on all WGs) ----
    {
      const float f = sc_s[0];
      float r = sigm(pr_s[tid]  + f*w1r_s[tid]);
      float z = sigm(pz_s[tid]  + f*w1z_s[tid]);
      float n = tanhf(pna_s[tid] + f*w1n_s[tid] + r*hn_s[tid]);
      h1_s[tid] = (1.f - z)*n + z*h_s[tid];
    }
    __syncthreads();

    // ---- (C) own 16 o1 rows (register weights), publish; then WX(t+1) fills the wait ----
    {
      float acc = 0.f;
      #pragma unroll
      for (int k=0;k<16;++k) acc += wO1r[k]*h1_s[c16*16 + k];
      acc += __shfl_xor(acc,1); acc += __shfl_xor(acc,2);
      acc += __shfl_xor(acc,4); acc += __shfl_xor(acc,8);
      if (c16 == 0) pub64(&sl[SL_O1 + g*16 + m16], pack_data(fmaxf(acc + bO1r, 0.f), tag));
    }
    COMPUTE_WX();                                  // xgb(t+1), consumed at (I)
    // ---- (D) gather o1 ----
    o_s[tid]       = spin_data(&sl[SL_O1 + (tid & 31)*16 + (tid >> 5)], tag);
    o_s[tid + 256] = spin_data(&sl[SL_O1 + (tid & 31)*16 + (tid >> 5) + 8], tag);
    __syncthreads();

    // ---- (E) O2 own 8 rows -> am1 publish ----
    {
      float acc = 0.f;
      #pragma unroll
      for (int k=0;k<16;++k) acc += wO2r[k]*o_s[l32 + 32*k];
      acc += __shfl_xor(acc,1); acc += __shfl_xor(acc,2); acc += __shfl_xor(acc,4);
      acc += __shfl_xor(acc,8); acc += __shfl_xor(acc,16);
      if (l32 == 0){ float v = acc + bO2; out_log[(size_t)t*512 + row2] = v; red_s[m8] = v; }
    }
    __syncthreads();
    if (tid == 0){
      float bv = red_s[0]; int bi = g;          // rows ascend with m -> strict > = first max
      #pragma unroll
      for (int m=1;m<8;++m){ float v = red_s[m]; if (v > bv){ bv = v; bi = g + 32*m; } }
      pub64(&sl[SL_AM1 + g],
            ((ull)__float_as_uint(bv) << 32) | ((ull)(unsigned)bi << 24) | tag);
    }
    // ---- (F) gather am1 -> c ----
    if (tid < 32){
      ull pk = spin_am(&sl[SL_AM1 + tid], tag);
      float bv = __uint_as_float((unsigned)(pk >> 32));
      int   bi = (int)((pk >> 24) & 0xFFu);
      #pragma unroll
      for (int off=16; off>=1; off>>=1){
        float ov = __shfl_xor(bv,off); int oi = __shfl_xor(bi,off);
        if (ov > bv || (ov == bv && oi < bi)){ bv = ov; bi = oi; }
      }
      if (tid == 0){ sc_s[2] = (float)bi; sc_s[3] = (float)bi/127.5f - 1.f; }
    }
    __syncthreads();

    // ---- (G) h2 local for ALL 512 elems (bit-identical on all WGs) ----
    {
      const float f = sc_s[0], cn = sc_s[3];
      #pragma unroll
      for (int hh=0; hh<2; ++hh){
        int e = tid + 256*hh;
        float r = sigm(pr_s[e]  + f*w1r_s[e] + cn*w2r_s[e]);
        float z = sigm(pz_s[e]  + f*w1z_s[e] + cn*w2z_s[e]);
        float n = tanhf(pna_s[e] + f*w1n_s[e] + cn*w2n_s[e] + r*hn_s[e]);
        h_s[e] = (1.f - z)*n + z*h_s[e];
      }
    }
    __syncthreads();

    // ---- (H) own 16 o3 rows from h2 upper half, publish ----
    {
      float acc = 0.f;
      #pragma unroll
      for (int k=0;k<16;++k) acc += wO3r[k]*h_s[256 + c16*16 + k];
      acc += __shfl_xor(acc,1); acc += __shfl_xor(acc,2);
      acc += __shfl_xor(acc,4); acc += __shfl_xor(acc,8);
      if (c16 == 0) pub64(&sl[SL_O3 + g*16 + m16], pack_data(fmaxf(acc + bO3r, 0.f), tag));
    }
    // ---- (I) WH(t+1) from local h2 + pre-gate publish(t+1) — fills the o3 wait ----
    COMPUTE_WH();
    __syncthreads();                               // hg_s/xgb_s complete
    if (t + 1 < T_STEPS) PUB_PREGATES((unsigned)(t + 2));
    // ---- (J) gather o3 ----
    o_s[tid]       = spin_data(&sl[SL_O3 + (tid & 31)*16 + (tid >> 5)], tag);
    o_s[tid + 256] = spin_data(&sl[SL_O3 + (tid & 31)*16 + (tid >> 5) + 8], tag);
    __syncthreads();

    // ---- (K) O4 own 8 rows -> am2 publish (parity bank); f gathered next step ----
    {
      float acc = 0.f;
      #pragma unroll
      for (int k=0;k<16;++k) acc += wO4r[k]*o_s[l32 + 32*k];
      acc += __shfl_xor(acc,1); acc += __shfl_xor(acc,2); acc += __shfl_xor(acc,4);
      acc += __shfl_xor(acc,8); acc += __shfl_xor(acc,16);
      if (l32 == 0){ float v = acc + bO4; out_log[(size_t)t*512 + 256 + row2] = v; red_s[m8] = v; }
    }
    __syncthreads();
    if (tid == 0){
      float bv = red_s[0]; int bi = g;
      #pragma unroll
      for (int m=1;m<8;++m){ float v = red_s[m]; if (v > bv){ bv = v; bi = g + 32*m; } }
      pub64(&sl[SL_AM2 + (t & 1)*32 + g],
            ((ull)__float_as_uint(bv) << 32) | ((ull)(unsigned)bi << 24) | tag);
    }
    // loop-top: gather am2 -> f(t+1)
  }

  // final sample: gather am2(T-1)
  if (g == 0 && tid < 32){
    ull pk = spin_am(&sl[SL_AM2 + ((T_STEPS-1) & 1)*32 + tid], (unsigned)T_STEPS);
    float bv = __uint_as_float((unsigned)(pk >> 32));
    int   bi = (int)((pk >> 24) & 0xFFu);
    #pragma unroll
    for (int off=16; off>=1; off>>=1){
      float ov = __shfl_xor(bv,off); int oi = __shfl_xor(bi,off);
      if (ov > bv || (ov == bv && oi < bi)){ bv = ov; bi = oi; }
    }
    if (tid == 0) out_samp[T_STEPS-1] = (sc_s[2]*256.f + (float)bi)/32767.5f - 1.f;
  }
}

extern "C" void kernel_launch(void* const* d_in, const int* in_sizes, int n_in,
                              void* d_out, int out_size, void* d_ws, size_t ws_size,
                              hipStream_t stream)
{
  const float* mels  = (const float*)d_in[0];
  const float* up_w0 = (const float*)d_in[1]; const float* up_b0 = (const float*)d_in[2];
  const float* up_w1 = (const float*)d_in[3]; const float* up_b1 = (const float*)d_in[4];
  const float* up_w2 = (const float*)d_in[5]; const float* up_b2 = (const float*)d_in[6];
  const float* Wx  = (const float*)d_in[7];  const float* bx  = (const float*)d_in[8];
  const float* Wh  = (const float*)d_in[9];  const float* bh  = (const float*)d_in[10];
  const float* O1w = (const float*)d_in[11]; const float* O1b = (const float*)d_in[12];
  const float* O2w = (const float*)d_in[13]; const float* O2b = (const float*)d_in[14];
  const float* O3w = (const float*)d_in[15]; const float* O3b = (const float*)d_in[16];
  const float* O4w = (const float*)d_in[17]; const float* O4b = (const float*)d_in[18];
  float* ws  = (float*)d_ws;
  float* out = (float*)d_out;

  k_init<<<(SL_END + 255)/256, 256, 0, stream>>>(ws);

  // upsample: 84 -> 412 -> 2052 -> 22552 (crop [1:-1] -> cond[22550][128])
  k_upconv<<<dim3((412  +127)/128, 128), 128, 0, stream>>>(mels,        86,   1, up_w0, up_b0,
            ws+OF_BUFA,  80,   84, 11,  5, 3,   412, 0);
  k_upconv<<<dim3((2052 +127)/128, 128), 128, 0, stream>>>(ws+OF_BUFA, 412,   0, up_w1, up_b1,
            ws+OF_BUFB, 128,  412, 11,  5, 3,  2052, 0);
  k_upconv<<<dim3((22552+127)/128, 128), 128, 0, stream>>>(ws+OF_BUFB, 2052,  0, up_w2, up_b2,
            ws+OF_COND, 128, 2052, 23, 11, 6, 22552, 1);

  k_wavernn<<<NWG, NTHR, 0, stream>>>(Wx, bx, Wh, bh, O1w, O1b, O2w, O2b,
                                      O3w, O3b, O4w, O4b, ws, out);
}